// Round 1
// baseline (886.091 us; speedup 1.0000x reference)
//
#include <hip/hip_runtime.h>

typedef __attribute__((ext_vector_type(8))) __bf16 bf16x8;
typedef __attribute__((ext_vector_type(4))) float f32x4;

#define SLEN 1024
#define DMODEL 1024
#define NHEADS 16
#define DKH 64
#define BATCH 8

__device__ __forceinline__ unsigned short f2bf(float f) {
  unsigned u = __builtin_bit_cast(unsigned, f);
  u += 0x7FFFu + ((u >> 16) & 1u);
  return (unsigned short)(u >> 16);
}

__device__ __forceinline__ void gload_lds16(const void* g, void* l) {
  __builtin_amdgcn_global_load_lds((const __attribute__((address_space(1))) unsigned int*)g,
                                   (__attribute__((address_space(3))) unsigned int*)l, 16, 0, 0);
}

// ---------------- mask dtype detection: flag=1 -> byte mask, 0 -> int32 mask
__global__ void detect_mask(const unsigned char* __restrict__ m, int* __restrict__ flag) {
  int t = threadIdx.x;
  unsigned any = 0;
  for (int j = t; j < 4096; j += 64) any |= m[j * 4 + 1];
  unsigned long long b = __ballot(any != 0);
  if (t == 0) *flag = (b != 0) ? 1 : 0;
}

// ---------------- fp32 -> bf16 bulk convert (8 elems/thread)
__global__ __launch_bounds__(256) void cvt_bf16(const float* __restrict__ in,
                                                unsigned short* __restrict__ o, int n8) {
  int i = blockIdx.x * 256 + threadIdx.x;
  if (i >= n8) return;
  const float4* p = (const float4*)in;
  float4 f0 = p[2 * i], f1 = p[2 * i + 1];
  union { unsigned short us[8]; uint4 v; } pk;
  pk.us[0] = f2bf(f0.x); pk.us[1] = f2bf(f0.y); pk.us[2] = f2bf(f0.z); pk.us[3] = f2bf(f0.w);
  pk.us[4] = f2bf(f1.x); pk.us[5] = f2bf(f1.y); pk.us[6] = f2bf(f1.z); pk.us[7] = f2bf(f1.w);
  ((uint4*)o)[i] = pk.v;
}

// ---------------- transpose V per (b,h): [1024][64] -> [64][1024]
__global__ __launch_bounds__(256) void transpose_v(const unsigned short* __restrict__ Vh,
                                                   unsigned short* __restrict__ Vt) {
  __shared__ unsigned short t[64][65];
  int s0 = blockIdx.x * 64;
  long zo = (long)blockIdx.y * (SLEN * DKH);
  int tid = threadIdx.x;
  for (int i = tid; i < 4096; i += 256) {
    int r = i >> 6, c = i & 63;
    t[r][c] = Vh[zo + (long)(s0 + r) * 64 + c];
  }
  __syncthreads();
  for (int i = tid; i < 4096; i += 256) {
    int d = i >> 6, sc = i & 63;
    Vt[zo + (long)d * SLEN + s0 + sc] = t[sc][d];
  }
}

// ---------------- generic NT bf16 MFMA GEMM: C[m,n] = sum_k A[m,k]*B[n,k]
// EPI: 0 = proj -> bf16 head layout (*scale), 1 = scores (+mask) -> fp32 attn,
//      2 = PV -> ctx bf16 [B*S][D], 3 = FC -> fp32 row-major
template<int BM, int BN, int WR, int WC, int EPI, bool AF32>
__global__ __launch_bounds__(256) void gemm_nt(
    const void* __restrict__ Av, const unsigned short* __restrict__ Bm,
    int K, int ldA, int ldB, long sA, long sB,
    float* __restrict__ of32, unsigned short* __restrict__ obf, float scale,
    const unsigned char* __restrict__ mask, const int* __restrict__ flag) {
  constexpr int BKE = 32;
  constexpr int WM = BM / WR, WN = BN / WC;
  constexpr int FM = WM / 16, FN = WN / 16;
  static_assert((BM * 4) % 256 == 0 && (BN * 4) % 256 == 0, "staging");

  const int m0 = blockIdx.x * BM;
  const int n0 = blockIdx.y * BN;
  const int z = blockIdx.z;
  const int tid = threadIdx.x;
  const int l = tid & 63;
  const int w = tid >> 6;
  const int wr = w / WC, wc = w % WC;

  __shared__ __attribute__((aligned(16))) unsigned short As[BM * BKE];
  __shared__ __attribute__((aligned(16))) unsigned short Bs[BN * BKE];

  const unsigned short* Ab = (const unsigned short*)Av + (AF32 ? 0 : (long)z * sA);
  const float* Af = (const float*)Av + (AF32 ? (long)z * sA : 0);
  const unsigned short* Bb = Bm + (long)z * sB;

  f32x4 acc[FM][FN];
#pragma unroll
  for (int i = 0; i < FM; i++)
#pragma unroll
    for (int j = 0; j < FN; j++)
      acc[i][j] = f32x4{0.f, 0.f, 0.f, 0.f};

  const int kread = (l >> 4) << 3;
  const int rl = l & 15;

  for (int k0 = 0; k0 < K; k0 += BKE) {
    __syncthreads();
    // stage A tile BMx32
#pragma unroll
    for (int i = 0; i < (BM * 4) / 256; i++) {
      int c = tid + i * 256;
      int row = c >> 2, kc = (c & 3) << 3;
      if constexpr (AF32) {
        const float* src = Af + (long)(m0 + row) * ldA + (k0 + kc);
        float4 f0 = ((const float4*)src)[0];
        float4 f1 = ((const float4*)src)[1];
        union { unsigned short us[8]; uint4 v; } pk;
        pk.us[0] = f2bf(f0.x); pk.us[1] = f2bf(f0.y); pk.us[2] = f2bf(f0.z); pk.us[3] = f2bf(f0.w);
        pk.us[4] = f2bf(f1.x); pk.us[5] = f2bf(f1.y); pk.us[6] = f2bf(f1.z); pk.us[7] = f2bf(f1.w);
        *(uint4*)&As[c * 8] = pk.v;
      } else {
        gload_lds16(Ab + (long)(m0 + row) * ldA + (k0 + kc), &As[c * 8]);
      }
    }
    // stage B tile BNx32
#pragma unroll
    for (int i = 0; i < (BN * 4) / 256; i++) {
      int c = tid + i * 256;
      int row = c >> 2, kc = (c & 3) << 3;
      gload_lds16(Bb + (long)(n0 + row) * ldB + (k0 + kc), &Bs[c * 8]);
    }
    __syncthreads();

    bf16x8 af[FM], bfr[FN];
#pragma unroll
    for (int mi = 0; mi < FM; mi++)
      af[mi] = *(const bf16x8*)&As[(wr * WM + mi * 16 + rl) * BKE + kread];
#pragma unroll
    for (int ni = 0; ni < FN; ni++)
      bfr[ni] = *(const bf16x8*)&Bs[(wc * WN + ni * 16 + rl) * BKE + kread];
#pragma unroll
    for (int mi = 0; mi < FM; mi++)
#pragma unroll
      for (int ni = 0; ni < FN; ni++)
        acc[mi][ni] = __builtin_amdgcn_mfma_f32_16x16x32_bf16(af[mi], bfr[ni], acc[mi][ni], 0, 0, 0);
  }

  // epilogue: C mapping col=lane&15, row=(lane>>4)*4+j
  const int r0 = (l >> 4) << 2;
  const int cc = l & 15;
  int mflag = 0;
  if constexpr (EPI == 1) mflag = *flag;
#pragma unroll
  for (int mi = 0; mi < FM; mi++) {
#pragma unroll
    for (int ni = 0; ni < FN; ni++) {
      f32x4 v = acc[mi][ni];
      int row = m0 + wr * WM + mi * 16 + r0;
      int col = n0 + wc * WN + ni * 16 + cc;
#pragma unroll
      for (int j = 0; j < 4; j++) {
        float val = v[j];
        int rr = row + j;
        if constexpr (EPI == 0) {
          long idx = (((long)((rr >> 10) * 16 + (col >> 6)) * 1024 + (rr & 1023)) << 6) + (col & 63);
          obf[idx] = f2bf(val * scale);
        } else if constexpr (EPI == 1) {
          int b = z >> 4;
          long mi_ = ((long)b << 20) + ((long)rr << 10) + col;
          bool msk = mflag ? (mask[mi_] != 0) : (((const int*)mask)[mi_] != 0);
          of32[((long)z << 20) + ((long)rr << 10) + col] = msk ? -1.0e9f : val;
        } else if constexpr (EPI == 2) {
          int b = z >> 4, h = z & 15;
          long idx = ((long)(b * 1024 + rr) << 10) + h * 64 + col;
          obf[idx] = f2bf(val);
        } else {
          of32[((long)rr << 10) + col] = val;
        }
      }
    }
  }
}

// ---------------- softmax over each row of 1024, in place on fp32 attn
__global__ __launch_bounds__(256) void softmax_rows(float* __restrict__ attn) {
  long base = (long)blockIdx.x << 10;
  int tid = threadIdx.x, l = tid & 63, w = tid >> 6;
  float4 v = ((float4*)(attn + base))[tid];
  float mx = fmaxf(fmaxf(v.x, v.y), fmaxf(v.z, v.w));
  for (int o = 32; o; o >>= 1) mx = fmaxf(mx, __shfl_xor(mx, o));
  __shared__ float r0[4], r1[4];
  if (l == 0) r0[w] = mx;
  __syncthreads();
  mx = fmaxf(fmaxf(r0[0], r0[1]), fmaxf(r0[2], r0[3]));
  float e0 = __expf(v.x - mx), e1 = __expf(v.y - mx);
  float e2 = __expf(v.z - mx), e3 = __expf(v.w - mx);
  float s = e0 + e1 + e2 + e3;
  for (int o = 32; o; o >>= 1) s += __shfl_xor(s, o);
  if (l == 0) r1[w] = s;
  __syncthreads();
  s = r1[0] + r1[1] + r1[2] + r1[3];
  float inv = 1.0f / s;
  float4 o4;
  o4.x = e0 * inv; o4.y = e1 * inv; o4.z = e2 * inv; o4.w = e3 * inv;
  ((float4*)(attn + base))[tid] = o4;
}

// ---------------- residual + LayerNorm, one block per row
__global__ __launch_bounds__(256) void ln_kernel(const float* __restrict__ fc,
                                                 const float* __restrict__ inQ,
                                                 const float* __restrict__ gamma,
                                                 const float* __restrict__ beta,
                                                 float* __restrict__ out) {
  long base = (long)blockIdx.x << 10;
  int tid = threadIdx.x, l = tid & 63, w = tid >> 6;
  float4 a = ((const float4*)(fc + base))[tid];
  float4 b = ((const float4*)(inQ + base))[tid];
  float4 x; x.x = a.x + b.x; x.y = a.y + b.y; x.z = a.z + b.z; x.w = a.w + b.w;
  float s = x.x + x.y + x.z + x.w;
  float q = x.x * x.x + x.y * x.y + x.z * x.z + x.w * x.w;
  for (int o = 32; o; o >>= 1) { s += __shfl_xor(s, o); q += __shfl_xor(q, o); }
  __shared__ float rs[4], rq[4];
  if (l == 0) { rs[w] = s; rq[w] = q; }
  __syncthreads();
  s = rs[0] + rs[1] + rs[2] + rs[3];
  q = rq[0] + rq[1] + rq[2] + rq[3];
  float mu = s * (1.0f / 1024.0f);
  float var = q * (1.0f / 1024.0f) - mu * mu;
  float rstd = rsqrtf(var + 1e-5f);
  float4 g = ((const float4*)gamma)[tid];
  float4 be = ((const float4*)beta)[tid];
  float4 o4;
  o4.x = (x.x - mu) * rstd * g.x + be.x;
  o4.y = (x.y - mu) * rstd * g.y + be.y;
  o4.z = (x.z - mu) * rstd * g.z + be.z;
  o4.w = (x.w - mu) * rstd * g.w + be.w;
  ((float4*)(out + base))[tid] = o4;
}

extern "C" void kernel_launch(void* const* d_in, const int* in_sizes, int n_in,
                              void* d_out, int out_size, void* d_ws, size_t ws_size,
                              hipStream_t stream) {
  const float* inQ = (const float*)d_in[0];
  const float* inK = (const float*)d_in[1];
  const float* inV = (const float*)d_in[2];
  const unsigned char* mask = (const unsigned char*)d_in[3];
  const float* WQ = (const float*)d_in[4];
  const float* WK = (const float*)d_in[5];
  const float* WV = (const float*)d_in[6];
  const float* WFC = (const float*)d_in[7];
  const float* gamma = (const float*)d_in[8];
  const float* beta = (const float*)d_in[9];

  float* out = (float*)d_out;
  float* attn = out + (size_t)BATCH * SLEN * DMODEL;  // second output, offset 8388608

  char* ws = (char*)d_ws;
  size_t off = 256;
  int* flag = (int*)ws;
  auto take = [&](size_t bytes) { char* p = ws + off; off += (bytes + 255) & ~255UL; return p; };
  const size_t XB = (size_t)BATCH * SLEN * DMODEL * 2;   // 16 MiB bf16
  const size_t WB = (size_t)DMODEL * DMODEL * 2;          // 2 MiB bf16
  unsigned short* Xq = (unsigned short*)take(XB);
  unsigned short* Xk = (unsigned short*)take(XB);
  unsigned short* Xv = (unsigned short*)take(XB);
  unsigned short* Wqb = (unsigned short*)take(WB);
  unsigned short* Wkb = (unsigned short*)take(WB);
  unsigned short* Wvb = (unsigned short*)take(WB);
  unsigned short* Wfcb = (unsigned short*)take(WB);
  unsigned short* Qh = (unsigned short*)take(XB);
  unsigned short* Kh = (unsigned short*)take(XB);
  unsigned short* Vh = (unsigned short*)take(XB);
  unsigned short* Vt = (unsigned short*)take(XB);
  unsigned short* ctx = (unsigned short*)take(XB);
  float* fc = (float*)take((size_t)BATCH * SLEN * DMODEL * 4);

  detect_mask<<<1, 64, 0, stream>>>(mask, flag);

  const int n8x = BATCH * SLEN * DMODEL / 8;  // 1048576
  const int n8w = DMODEL * DMODEL / 8;        // 131072
  cvt_bf16<<<n8x / 256, 256, 0, stream>>>(inQ, Xq, n8x);
  cvt_bf16<<<n8x / 256, 256, 0, stream>>>(inK, Xk, n8x);
  cvt_bf16<<<n8x / 256, 256, 0, stream>>>(inV, Xv, n8x);
  cvt_bf16<<<n8w / 256, 256, 0, stream>>>(WQ, Wqb, n8w);
  cvt_bf16<<<n8w / 256, 256, 0, stream>>>(WK, Wkb, n8w);
  cvt_bf16<<<n8w / 256, 256, 0, stream>>>(WV, Wvb, n8w);
  cvt_bf16<<<n8w / 256, 256, 0, stream>>>(WFC, Wfcb, n8w);

  // projections: M=8192, N=1024, K=1024 ; Q pre-scaled by 1/sqrt(64)
  dim3 gp(64, 8, 1);
  gemm_nt<128, 128, 2, 2, 0, false><<<gp, 256, 0, stream>>>(
      Xq, Wqb, 1024, 1024, 1024, 0, 0, nullptr, Qh, 0.125f, nullptr, nullptr);
  gemm_nt<128, 128, 2, 2, 0, false><<<gp, 256, 0, stream>>>(
      Xk, Wkb, 1024, 1024, 1024, 0, 0, nullptr, Kh, 1.0f, nullptr, nullptr);
  gemm_nt<128, 128, 2, 2, 0, false><<<gp, 256, 0, stream>>>(
      Xv, Wvb, 1024, 1024, 1024, 0, 0, nullptr, Vh, 1.0f, nullptr, nullptr);

  transpose_v<<<dim3(16, 128, 1), 256, 0, stream>>>(Vh, Vt);

  // scores + mask -> attn region (fp32), per (b,h)
  dim3 gs(8, 8, 128);
  gemm_nt<128, 128, 2, 2, 1, false><<<gs, 256, 0, stream>>>(
      Qh, Kh, 64, 64, 64, SLEN * DKH, SLEN * DKH, attn, nullptr, 1.0f, mask, flag);

  softmax_rows<<<BATCH * NHEADS * SLEN, 256, 0, stream>>>(attn);

  // PV: ctx[q, h*64+d] = sum_m attn[q,m] * Vt[d,m]
  dim3 gv(8, 1, 128);
  gemm_nt<128, 64, 4, 1, 2, true><<<gv, 256, 0, stream>>>(
      attn, Vt, 1024, 1024, 1024, (long)SLEN * SLEN, SLEN * DKH, nullptr, ctx, 1.0f, nullptr, nullptr);

  // FC: fp32 out to ws
  gemm_nt<128, 128, 2, 2, 3, false><<<gp, 256, 0, stream>>>(
      ctx, Wfcb, 1024, 1024, 1024, 0, 0, fc, nullptr, 1.0f, nullptr, nullptr);

  ln_kernel<<<BATCH * SLEN, 256, 0, stream>>>(fc, inQ, gamma, beta, out);
}